// Round 2
// baseline (6039.777 us; speedup 1.0000x reference)
//
#include <hip/hip_runtime.h>
#include <hip/hip_bf16.h>

typedef __hip_bfloat16 bf16;
typedef unsigned short u16;

#define BATCH 512
#define CW_DIM 4096
#define DIM_CODES 64
#define BOOK_SIZE 1024
#define DIM_EMBED 64
#define ENC_H 512

// ---------------- dtype helpers (bf=1 -> bf16 inputs, bf=0 -> fp32) ----------------
__device__ __forceinline__ float bf2f(u16 u) {
    unsigned int x = ((unsigned int)u) << 16;
    return __uint_as_float(x);
}
__device__ __forceinline__ float loadf(const void* p, size_t i, int bf) {
    if (bf) return bf2f(((const u16*)p)[i]);
    return ((const float*)p)[i];
}
__device__ __forceinline__ double loadd(const void* p, size_t i, int bf) {
    return (double)loadf(p, i, bf);
}
// vector load of 4 consecutive elements (i must be a multiple of 4)
__device__ __forceinline__ float4 load4(const void* p, size_t i, int bf) {
    if (bf) {
        const u16* q = (const u16*)p + i;
        uint2 raw = *reinterpret_cast<const uint2*>(q);
        float4 r;
        r.x = bf2f((u16)(raw.x & 0xFFFF));
        r.y = bf2f((u16)(raw.x >> 16));
        r.z = bf2f((u16)(raw.y & 0xFFFF));
        r.w = bf2f((u16)(raw.y >> 16));
        return r;
    }
    return *reinterpret_cast<const float4*>((const float*)p + i);
}
__device__ __forceinline__ void stored(void* p, size_t i, int bf, double v) {
    if (bf) ((bf16*)p)[i] = __float2bfloat16((float)v);
    else    ((float*)p)[i] = (float)v;
}
__device__ __forceinline__ u16 f2bfu(float v) {
    bf16 b = __float2bfloat16(v);
    return *reinterpret_cast<u16*>(&b);
}

// ---------------- dtype detector ----------------
__global__ void detect_kernel(const u16* __restrict__ x, int* __restrict__ flag) {
    __shared__ int hits;
    if (threadIdx.x == 0) hits = 0;
    __syncthreads();
    int h = 0;
    for (int i = threadIdx.x; i < 16384; i += 256) {
        u16 v = x[2 * i];
        if (((v >> 7) & 0xFF) == 0xFF) h++;
    }
    atomicAdd(&hits, h);
    __syncthreads();
    if (threadIdx.x == 0) *flag = (hits == 0) ? 1 : 0;  // 1 = bf16, 0 = fp32
}

// ---------------- codebook row norms (fp64, vectorized loads) ----------------
__global__ void booknorm_kernel(const void* __restrict__ book, double* __restrict__ bn,
                                const int* __restrict__ dflag) {
    const int bf = *dflag;
    int r = blockIdx.x * blockDim.x + threadIdx.x;
    if (r >= DIM_CODES * BOOK_SIZE) return;
    double acc = 0.0;
    for (int e = 0; e < DIM_EMBED; e += 4) {
        float4 v = load4(book, (size_t)r * DIM_EMBED + e, bf);
        acc = fma((double)v.x, (double)v.x, acc);
        acc = fma((double)v.y, (double)v.y, acc);
        acc = fma((double)v.z, (double)v.z, acc);
        acc = fma((double)v.w, (double)v.w, acc);
    }
    bn[r] = acc;
}

// ---------------- encoder conv + maxpool: 64c x 64h register-tiled mini-GEMM ----------------
// grid (8 h-tiles, 512 b); transposed LDS operands -> ds_read_b128 fragments.
__global__ __launch_bounds__(256) void enc_kernel(const void* __restrict__ x,
                                                  const void* __restrict__ w1,
                                                  const void* __restrict__ b1,
                                                  float* __restrict__ hmax,
                                                  const int* __restrict__ dflag) {
    const int bf = *dflag;
    __shared__ float xs_t[64][68];   // [e][c]
    __shared__ float wsh_t[64][68];  // [e][h]
    __shared__ float red[64][17];
    int t = threadIdx.x;
    int h0 = blockIdx.x * 64;
    int b = blockIdx.y;

    // stage + transpose: thread loads 4 float4 along e of one row
    int cr = t >> 2;             // 0..63 (c row for x, h row for w1)
    int e0 = (t & 3) << 4;       // 0,16,32,48
    for (int q = 0; q < 4; q++) {
        int e = e0 + (q << 2);
        float4 xv = load4(x, (size_t)b * CW_DIM + cr * DIM_EMBED + e, bf);
        xs_t[e + 0][cr] = xv.x; xs_t[e + 1][cr] = xv.y;
        xs_t[e + 2][cr] = xv.z; xs_t[e + 3][cr] = xv.w;
        float4 wv = load4(w1, (size_t)(h0 + cr) * DIM_EMBED + e, bf);
        wsh_t[e + 0][cr] = wv.x; wsh_t[e + 1][cr] = wv.y;
        wsh_t[e + 2][cr] = wv.z; wsh_t[e + 3][cr] = wv.w;
    }
    __syncthreads();

    int th = t & 15, tc = t >> 4;   // thread tile: 4 c x 4 h
    float acc[4][4] = {};
    for (int e = 0; e < 64; e++) {
        float4 a4 = *(const float4*)&xs_t[e][tc << 2];
        float4 w4 = *(const float4*)&wsh_t[e][th << 2];
        float aa[4] = {a4.x, a4.y, a4.z, a4.w};
        float ww[4] = {w4.x, w4.y, w4.z, w4.w};
#pragma unroll
        for (int i = 0; i < 4; i++)
#pragma unroll
            for (int j = 0; j < 4; j++)
                acc[i][j] = fmaf(aa[i], ww[j], acc[i][j]);
    }
#pragma unroll
    for (int j = 0; j < 4; j++) {
        float bj = loadf(b1, h0 + (th << 2) + j, bf);
        float m = -1e30f;
#pragma unroll
        for (int i = 0; i < 4; i++) {
            float v = acc[i][j] + bj;
            v = v > 0.f ? v : 0.2f * v;
            m = fmaxf(m, v);
        }
        red[(th << 2) + j][tc] = m;
    }
    __syncthreads();
    if (t < 64) {
        float m = red[t][0];
        for (int k = 1; k < 16; k++) m = fmaxf(m, red[t][k]);
        hmax[(size_t)b * ENC_H + h0 + t] = m;
    }
}

// ---------------- fp32 GEMM: C[M,N] = act(A @ W^T + bias) ----------------
// A logically [M,Ktot]: cols [0,K1) from A1 (stride lda1), rest from A2 (stride lda2).
// 64x64 block tile, BK=16, 4x4 per thread, float4 staging + b128 LDS reads.
__global__ __launch_bounds__(256) void gemm_kernel(const float* __restrict__ A1, int lda1, int K1,
                                                   const float* __restrict__ A2, int lda2, int Ktot,
                                                   const void* __restrict__ W,
                                                   const void* __restrict__ bias,
                                                   float* __restrict__ C, int N, int act,
                                                   const int* __restrict__ dflag) {
    const int bf = *dflag;
    __shared__ float As[16][68];
    __shared__ float Ws[16][68];
    int t = threadIdx.x;
    int tx = t & 15, ty = t >> 4;
    int n0 = blockIdx.x * 64, m0 = blockIdx.y * 64;
    int mrow = t >> 2, kq = (t & 3) << 2;  // each thread stages one float4 of A and of W
    float acc[4][4] = {};
    for (int kt = 0; kt < Ktot; kt += 16) {
        int k = kt + kq;
        float4 av;
        if (k < K1) av = *reinterpret_cast<const float4*>(A1 + (size_t)(m0 + mrow) * lda1 + k);
        else        av = *reinterpret_cast<const float4*>(A2 + (size_t)(m0 + mrow) * lda2 + (k - K1));
        float4 wv = load4(W, (size_t)(n0 + mrow) * Ktot + k, bf);
        As[kq + 0][mrow] = av.x; As[kq + 1][mrow] = av.y;
        As[kq + 2][mrow] = av.z; As[kq + 3][mrow] = av.w;
        Ws[kq + 0][mrow] = wv.x; Ws[kq + 1][mrow] = wv.y;
        Ws[kq + 2][mrow] = wv.z; Ws[kq + 3][mrow] = wv.w;
        __syncthreads();
#pragma unroll
        for (int kk = 0; kk < 16; kk++) {
            float4 a4 = *(const float4*)&As[kk][ty << 2];
            float4 w4 = *(const float4*)&Ws[kk][tx << 2];
            float a[4] = {a4.x, a4.y, a4.z, a4.w};
            float w[4] = {w4.x, w4.y, w4.z, w4.w};
#pragma unroll
            for (int i = 0; i < 4; i++)
#pragma unroll
                for (int j = 0; j < 4; j++)
                    acc[i][j] = fmaf(a[i], w[j], acc[i][j]);
        }
        __syncthreads();
    }
#pragma unroll
    for (int i = 0; i < 4; i++) {
        int m = m0 + (ty << 2) + i;
        float ov[4];
#pragma unroll
        for (int j = 0; j < 4; j++) {
            int n = n0 + (tx << 2) + j;
            float v = acc[i][j] + loadf(bias, n, bf);
            if (act) v = v > 0.f ? v : 0.2f * v;
            ov[j] = v;
        }
        float4 o = {ov[0], ov[1], ov[2], ov[3]};
        *reinterpret_cast<float4*>(C + (size_t)m * N + n0 + (tx << 2)) = o;
    }
}

// ---------------- z2 = dfull[:, :768] + pfull[:, :768], float4 ----------------
__global__ void add_kernel(const float* __restrict__ a, int lda_a,
                           const float* __restrict__ b, int lda_b,
                           float* __restrict__ o, int ncolq, int total4) {
    int g = blockIdx.x * blockDim.x + threadIdx.x;
    if (g >= total4) return;
    int m = g / ncolq, j = (g % ncolq) << 2;
    float4 va = *reinterpret_cast<const float4*>(a + (size_t)m * lda_a + j);
    float4 vb = *reinterpret_cast<const float4*>(b + (size_t)m * lda_b + j);
    float4 vo = {va.x + vb.x, va.y + vb.y, va.z + vb.z, va.w + vb.w};
    *reinterpret_cast<float4*>(o + (size_t)g * 4) = vo;
}

// ---------------- strided fp32 -> output-dtype cast, vectorized x4 ----------------
__global__ void cast_kernel(const float* __restrict__ src, int lda, int col0, int ncolq,
                            void* __restrict__ out, size_t obase, int total4,
                            const int* __restrict__ dflag) {
    const int bf = *dflag;
    int g = blockIdx.x * blockDim.x + threadIdx.x;
    if (g >= total4) return;
    int m = g / ncolq, j = (g % ncolq) << 2;
    float4 v = *reinterpret_cast<const float4*>(src + (size_t)m * lda + col0 + j);
    if (bf) {
        ushort4 h;
        h.x = f2bfu(v.x); h.y = f2bfu(v.y); h.z = f2bfu(v.z); h.w = f2bfu(v.w);
        *reinterpret_cast<ushort4*>((u16*)out + obase + (size_t)g * 4) = h;
    } else {
        *reinterpret_cast<float4*>((float*)out + obase + (size_t)g * 4) = v;
    }
}

// ---------------- fused cw_dist (fp64) + exact argmin ----------------
// grid (c=64, btile=16); block 256 = 4 waves; block covers 32 b-rows x 1024 s.
// bs hoisted out of p-loop: per e-pair 1 b64 (bs) + 8 broadcast b128 (xs).
__global__ __launch_bounds__(256) void dist_kernel(const float* __restrict__ cwr,
                                                   const void* __restrict__ book,
                                                   const double* __restrict__ bn,
                                                   void* __restrict__ out,
                                                   size_t odist, size_t oidx,
                                                   const int* __restrict__ dflag) {
    const int bf = *dflag;
    __shared__ double xs[32][64];   // 16 KB
    __shared__ double xn[32];
    __shared__ float bs[64][66];    // 66 pad: float2-aligned, 2-way banks (free)
    int t = threadIdx.x;
    int c = blockIdx.x;
    int b0 = blockIdx.y * 32;
    int sl = t & 63, wv = t >> 6;

    for (int i = t; i < 32 * 64; i += 256) {
        int bl = i >> 6, e = i & 63;
        xs[bl][e] = (double)cwr[(size_t)(b0 + bl) * CW_DIM + c * DIM_EMBED + e];
    }
    __syncthreads();
    if (t < 32) {
        double a = 0.0;
        for (int e = 0; e < 64; e++) a = fma(xs[t][e], xs[t][e], a);
        xn[t] = a;
    }

    double bd[8];
    int bsx[8];
#pragma unroll
    for (int p = 0; p < 8; p++) { bd[p] = 1e300; bsx[p] = 0; }

    for (int st = 0; st < 16; st++) {
        int s0 = st * 64;
        __syncthreads();  // previous-tile readers done (and xn visible on st==0)
        for (int i4 = t; i4 < 1024; i4 += 256) {
            int srow = i4 >> 4, e4 = (i4 & 15) << 2;
            float4 v = load4(book, ((size_t)c * BOOK_SIZE + s0 + srow) * DIM_EMBED + e4, bf);
            bs[srow][e4 + 0] = v.x; bs[srow][e4 + 1] = v.y;
            bs[srow][e4 + 2] = v.z; bs[srow][e4 + 3] = v.w;
        }
        __syncthreads();
        double bnv = bn[(size_t)c * BOOK_SIZE + s0 + sl];
        double acc[8] = {0, 0, 0, 0, 0, 0, 0, 0};
        for (int e = 0; e < 64; e += 2) {
            float2 bv = *(const float2*)&bs[sl][e];
            double bv0 = (double)bv.x, bv1 = (double)bv.y;
#pragma unroll
            for (int p = 0; p < 8; p++) {
                int bl = wv * 8 + p;
                acc[p] = fma(xs[bl][e], bv0, acc[p]);
                acc[p] = fma(xs[bl][e + 1], bv1, acc[p]);
            }
        }
#pragma unroll
        for (int p = 0; p < 8; p++) {
            int bl = wv * 8 + p;
            double d = xn[bl] + bnv - 2.0 * acc[p];
            stored(out, odist + ((size_t)(b0 + bl) * DIM_CODES + c) * BOOK_SIZE + s0 + sl, bf, d);
            if (d < bd[p]) { bd[p] = d; bsx[p] = s0 + sl; }
        }
    }
#pragma unroll
    for (int p = 0; p < 8; p++) {
        double d = bd[p];
        int s = bsx[p];
        for (int off = 32; off >= 1; off >>= 1) {
            double od = __shfl_xor(d, off, 64);
            int os = __shfl_xor(s, off, 64);
            if (od < d || (od == d && os < s)) { d = od; s = os; }
        }
        if (sl == 0)
            stored(out, oidx + (size_t)(b0 + wv * 8 + p) * DIM_CODES + c, bf, (double)s);
    }
}

extern "C" void kernel_launch(void* const* d_in, const int* in_sizes, int n_in,
                              void* d_out, int out_size, void* d_ws, size_t ws_size,
                              hipStream_t stream) {
    const void* x        = d_in[0];
    const void* codebook = d_in[1];
    const void* enc_w1   = d_in[2];
    const void* enc_b1   = d_in[3];
    const void* enc_w2   = d_in[4];
    const void* enc_b2   = d_in[5];
    const void* inf1_w   = d_in[6];
    const void* inf1_b   = d_in[7];
    const void* inf2_w1  = d_in[8];
    const void* inf2_b1  = d_in[9];
    const void* inf2_w2  = d_in[10];
    const void* inf2_b2  = d_in[11];
    const void* prior_w1 = d_in[12];
    const void* prior_b1 = d_in[13];
    const void* prior_w2 = d_in[14];
    const void* prior_b2 = d_in[15];
    const void* dec_w1   = d_in[16];
    const void* dec_b1   = d_in[17];
    const void* dec_w2   = d_in[18];
    const void* dec_b2   = d_in[19];

    // ---- fp32 workspace with aliasing (~26 MB, was ~52 MB in fp64) ----
    float* W0 = (float*)d_ws;
    float* inf1out = W0;                   // 512*512           [live to end]
    float* pfull   = inf1out + 262144;     // 512*1536          [live to end]
    float* dfull   = pfull + 786432;       // 512*1536          [live to end]
    float* cwr     = dfull + 786432;       // 512*4096          [live to end]
    float* bufA    = cwr + 2097152;        // 512*2048: h2, later dech
    float* bufB    = bufA + 1048576;       // 512*2048: p1, later d1
    float* bufC    = bufB + 1048576;       // 512*768: hmax(512*512), later z2
    double* bn     = (double*)(bufC + 393216);  // 64*1024 doubles (offset 8B-aligned)
    int* dflag     = (int*)(bn + 65536);

    // ---- output slice element offsets (return order) ----
    const size_t o_cwrecon = 0;
    const size_t o_cwdist  = 2097152;
    const size_t o_idx     = 35651584;
    const size_t o_mu      = 35684352;
    const size_t o_logvar  = 35815424;
    const size_t o_dmu     = 35946496;
    const size_t o_dlogvar = 36339712;
    const size_t o_plogvar = 36732928;

    detect_kernel<<<1, 256, 0, stream>>>((const u16*)x, dflag);
    booknorm_kernel<<<256, 256, 0, stream>>>(codebook, bn, dflag);
    enc_kernel<<<dim3(8, BATCH), 256, 0, stream>>>(x, enc_w1, enc_b1, bufC, dflag);  // hmax -> bufC

    // h2 = hmax @ enc_w2^T
    gemm_kernel<<<dim3(32, 8), 256, 0, stream>>>(bufC, 512, 512, bufC, 512, 512,
                                                 enc_w2, enc_b2, bufA, 2048, 0, dflag);
    // inf1out = h2 @ inf1_w^T (mu | log_var)
    gemm_kernel<<<dim3(8, 8), 256, 0, stream>>>(bufA, 2048, 2048, bufA, 2048, 2048,
                                                inf1_w, inf1_b, inf1out, 512, 0, dflag);
    // p1 = lrelu(z1 @ prior_w1^T); z1 = inf1out[:, :256]
    gemm_kernel<<<dim3(32, 8), 256, 0, stream>>>(inf1out, 512, 256, inf1out, 512, 256,
                                                 prior_w1, prior_b1, bufB, 2048, 1, dflag);
    // pfull = p1 @ prior_w2^T
    gemm_kernel<<<dim3(24, 8), 256, 0, stream>>>(bufB, 2048, 2048, bufB, 2048, 2048,
                                                 prior_w2, prior_b2, pfull, 1536, 0, dflag);
    // d1 = lrelu(concat(z1, h2) @ inf2_w1^T)   (overwrites p1, dead)
    gemm_kernel<<<dim3(32, 8), 256, 0, stream>>>(inf1out, 512, 256, bufA, 2048, 2304,
                                                 inf2_w1, inf2_b1, bufB, 2048, 1, dflag);
    // dfull = d1 @ inf2_w2^T
    gemm_kernel<<<dim3(24, 8), 256, 0, stream>>>(bufB, 2048, 2048, bufB, 2048, 2048,
                                                 inf2_w2, inf2_b2, dfull, 1536, 0, dflag);
    // z2 = dfull[:, :768] + pfull[:, :768]   (hmax dead -> bufC)
    add_kernel<<<384, 256, 0, stream>>>(dfull, 1536, pfull, 1536, bufC, 192, 98304);
    // dech = lrelu(z2 @ dec_w1^T)   (h2 dead -> bufA)
    gemm_kernel<<<dim3(32, 8), 256, 0, stream>>>(bufC, 768, 768, bufC, 768, 768,
                                                 dec_w1, dec_b1, bufA, 2048, 1, dflag);
    // cwr = dech @ dec_w2^T
    gemm_kernel<<<dim3(64, 8), 256, 0, stream>>>(bufA, 2048, 2048, bufA, 2048, 2048,
                                                 dec_w2, dec_b2, cwr, 4096, 0, dflag);

    // fused distances + argmin (writes o_cwdist and o_idx directly; fp64 kept here)
    dist_kernel<<<dim3(64, 16), 256, 0, stream>>>(cwr, codebook, bn,
                                                  d_out, o_cwdist, o_idx, dflag);

    // output casts (vectorized x4)
    cast_kernel<<<2048, 256, 0, stream>>>(cwr, 4096, 0, 1024, d_out, o_cwrecon, 524288, dflag);
    cast_kernel<<<128, 256, 0, stream>>>(inf1out, 512, 0, 64, d_out, o_mu, 32768, dflag);
    cast_kernel<<<128, 256, 0, stream>>>(inf1out, 512, 256, 64, d_out, o_logvar, 32768, dflag);
    cast_kernel<<<384, 256, 0, stream>>>(dfull, 1536, 0, 192, d_out, o_dmu, 98304, dflag);
    cast_kernel<<<384, 256, 0, stream>>>(dfull, 1536, 768, 192, d_out, o_dlogvar, 98304, dflag);
    cast_kernel<<<384, 256, 0, stream>>>(pfull, 1536, 768, 192, d_out, o_plogvar, 98304, dflag);
}

// Round 3
// 1181.042 us; speedup vs baseline: 5.1139x; 5.1139x over previous
//
#include <hip/hip_runtime.h>
#include <hip/hip_bf16.h>

typedef __hip_bfloat16 bf16;
typedef unsigned short u16;

#define BATCH 512
#define CW_DIM 4096
#define DIM_CODES 64
#define BOOK_SIZE 1024
#define DIM_EMBED 64
#define ENC_H 512

// ---------------- dtype helpers (bf=1 -> bf16 inputs, bf=0 -> fp32) ----------------
__device__ __forceinline__ float bf2f(u16 u) {
    unsigned int x = ((unsigned int)u) << 16;
    return __uint_as_float(x);
}
__device__ __forceinline__ float loadf(const void* p, size_t i, int bf) {
    if (bf) return bf2f(((const u16*)p)[i]);
    return ((const float*)p)[i];
}
__device__ __forceinline__ double loadd(const void* p, size_t i, int bf) {
    return (double)loadf(p, i, bf);
}
// vector load of 4 consecutive elements (i must be a multiple of 4)
__device__ __forceinline__ float4 load4(const void* p, size_t i, int bf) {
    if (bf) {
        const u16* q = (const u16*)p + i;
        uint2 raw = *reinterpret_cast<const uint2*>(q);
        float4 r;
        r.x = bf2f((u16)(raw.x & 0xFFFF));
        r.y = bf2f((u16)(raw.x >> 16));
        r.z = bf2f((u16)(raw.y & 0xFFFF));
        r.w = bf2f((u16)(raw.y >> 16));
        return r;
    }
    return *reinterpret_cast<const float4*>((const float*)p + i);
}
__device__ __forceinline__ void stored(void* p, size_t i, int bf, double v) {
    if (bf) ((bf16*)p)[i] = __float2bfloat16((float)v);
    else    ((float*)p)[i] = (float)v;
}
__device__ __forceinline__ u16 f2bfu(float v) {
    bf16 b = __float2bfloat16(v);
    return *reinterpret_cast<u16*>(&b);
}

// ---------------- dtype detector ----------------
__global__ void detect_kernel(const u16* __restrict__ x, int* __restrict__ flag) {
    __shared__ int hits;
    if (threadIdx.x == 0) hits = 0;
    __syncthreads();
    int h = 0;
    for (int i = threadIdx.x; i < 16384; i += 256) {
        u16 v = x[2 * i];
        if (((v >> 7) & 0xFF) == 0xFF) h++;
    }
    atomicAdd(&hits, h);
    __syncthreads();
    if (threadIdx.x == 0) *flag = (hits == 0) ? 1 : 0;  // 1 = bf16, 0 = fp32
}

// ---------------- codebook row norms (fp64, vectorized loads) ----------------
__global__ void booknorm_kernel(const void* __restrict__ book, double* __restrict__ bn,
                                const int* __restrict__ dflag) {
    const int bf = *dflag;
    int r = blockIdx.x * blockDim.x + threadIdx.x;
    if (r >= DIM_CODES * BOOK_SIZE) return;
    double acc = 0.0;
    for (int e = 0; e < DIM_EMBED; e += 4) {
        float4 v = load4(book, (size_t)r * DIM_EMBED + e, bf);
        acc = fma((double)v.x, (double)v.x, acc);
        acc = fma((double)v.y, (double)v.y, acc);
        acc = fma((double)v.z, (double)v.z, acc);
        acc = fma((double)v.w, (double)v.w, acc);
    }
    bn[r] = acc;
}

// ---------------- encoder conv + maxpool: 64c x 64h register-tiled mini-GEMM ----------------
// grid (8 h-tiles, 512 b); transposed LDS operands -> ds_read_b128 fragments.
__global__ __launch_bounds__(256) void enc_kernel(const void* __restrict__ x,
                                                  const void* __restrict__ w1,
                                                  const void* __restrict__ b1,
                                                  float* __restrict__ hmax,
                                                  const int* __restrict__ dflag) {
    const int bf = *dflag;
    __shared__ float xs_t[64][68];   // [e][c]
    __shared__ float wsh_t[64][68];  // [e][h]
    __shared__ float red[64][17];
    int t = threadIdx.x;
    int h0 = blockIdx.x * 64;
    int b = blockIdx.y;

    // stage + transpose: thread loads 4 float4 along e of one row
    int cr = t >> 2;             // 0..63 (c row for x, h row for w1)
    int e0 = (t & 3) << 4;       // 0,16,32,48
    for (int q = 0; q < 4; q++) {
        int e = e0 + (q << 2);
        float4 xv = load4(x, (size_t)b * CW_DIM + cr * DIM_EMBED + e, bf);
        xs_t[e + 0][cr] = xv.x; xs_t[e + 1][cr] = xv.y;
        xs_t[e + 2][cr] = xv.z; xs_t[e + 3][cr] = xv.w;
        float4 wv = load4(w1, (size_t)(h0 + cr) * DIM_EMBED + e, bf);
        wsh_t[e + 0][cr] = wv.x; wsh_t[e + 1][cr] = wv.y;
        wsh_t[e + 2][cr] = wv.z; wsh_t[e + 3][cr] = wv.w;
    }
    __syncthreads();

    int th = t & 15, tc = t >> 4;   // thread tile: 4 c x 4 h
    float acc[4][4] = {};
    for (int e = 0; e < 64; e++) {
        float4 a4 = *(const float4*)&xs_t[e][tc << 2];
        float4 w4 = *(const float4*)&wsh_t[e][th << 2];
        float aa[4] = {a4.x, a4.y, a4.z, a4.w};
        float ww[4] = {w4.x, w4.y, w4.z, w4.w};
#pragma unroll
        for (int i = 0; i < 4; i++)
#pragma unroll
            for (int j = 0; j < 4; j++)
                acc[i][j] = fmaf(aa[i], ww[j], acc[i][j]);
    }
#pragma unroll
    for (int j = 0; j < 4; j++) {
        float bj = loadf(b1, h0 + (th << 2) + j, bf);
        float m = -1e30f;
#pragma unroll
        for (int i = 0; i < 4; i++) {
            float v = acc[i][j] + bj;
            v = v > 0.f ? v : 0.2f * v;
            m = fmaxf(m, v);
        }
        red[(th << 2) + j][tc] = m;
    }
    __syncthreads();
    if (t < 64) {
        float m = red[t][0];
        for (int k = 1; k < 16; k++) m = fmaxf(m, red[t][k]);
        hmax[(size_t)b * ENC_H + h0 + t] = m;
    }
}

// ---------------- fp32 GEMM: C[M,N] = act(A @ W^T + bias) ----------------
// A logically [M,Ktot]: cols [0,K1) from A1 (stride lda1), rest from A2 (stride lda2).
// 64x64 block tile, BK=16, 4x4 per thread, float4 staging + b128 LDS reads.
__global__ __launch_bounds__(256) void gemm_kernel(const float* __restrict__ A1, int lda1, int K1,
                                                   const float* __restrict__ A2, int lda2, int Ktot,
                                                   const void* __restrict__ W,
                                                   const void* __restrict__ bias,
                                                   float* __restrict__ C, int N, int act,
                                                   const int* __restrict__ dflag) {
    const int bf = *dflag;
    __shared__ float As[16][68];
    __shared__ float Ws[16][68];
    int t = threadIdx.x;
    int tx = t & 15, ty = t >> 4;
    int n0 = blockIdx.x * 64, m0 = blockIdx.y * 64;
    int mrow = t >> 2, kq = (t & 3) << 2;  // each thread stages one float4 of A and of W
    float acc[4][4] = {};
    for (int kt = 0; kt < Ktot; kt += 16) {
        int k = kt + kq;
        float4 av;
        if (k < K1) av = *reinterpret_cast<const float4*>(A1 + (size_t)(m0 + mrow) * lda1 + k);
        else        av = *reinterpret_cast<const float4*>(A2 + (size_t)(m0 + mrow) * lda2 + (k - K1));
        float4 wv = load4(W, (size_t)(n0 + mrow) * Ktot + k, bf);
        As[kq + 0][mrow] = av.x; As[kq + 1][mrow] = av.y;
        As[kq + 2][mrow] = av.z; As[kq + 3][mrow] = av.w;
        Ws[kq + 0][mrow] = wv.x; Ws[kq + 1][mrow] = wv.y;
        Ws[kq + 2][mrow] = wv.z; Ws[kq + 3][mrow] = wv.w;
        __syncthreads();
#pragma unroll
        for (int kk = 0; kk < 16; kk++) {
            float4 a4 = *(const float4*)&As[kk][ty << 2];
            float4 w4 = *(const float4*)&Ws[kk][tx << 2];
            float a[4] = {a4.x, a4.y, a4.z, a4.w};
            float w[4] = {w4.x, w4.y, w4.z, w4.w};
#pragma unroll
            for (int i = 0; i < 4; i++)
#pragma unroll
                for (int j = 0; j < 4; j++)
                    acc[i][j] = fmaf(a[i], w[j], acc[i][j]);
        }
        __syncthreads();
    }
#pragma unroll
    for (int i = 0; i < 4; i++) {
        int m = m0 + (ty << 2) + i;
        float ov[4];
#pragma unroll
        for (int j = 0; j < 4; j++) {
            int n = n0 + (tx << 2) + j;
            float v = acc[i][j] + loadf(bias, n, bf);
            if (act) v = v > 0.f ? v : 0.2f * v;
            ov[j] = v;
        }
        float4 o = {ov[0], ov[1], ov[2], ov[3]};
        *reinterpret_cast<float4*>(C + (size_t)m * N + n0 + (tx << 2)) = o;
    }
}

// ---------------- z2 = dfull[:, :768] + pfull[:, :768], float4 ----------------
__global__ void add_kernel(const float* __restrict__ a, int lda_a,
                           const float* __restrict__ b, int lda_b,
                           float* __restrict__ o, int ncolq, int total4) {
    int g = blockIdx.x * blockDim.x + threadIdx.x;
    if (g >= total4) return;
    int m = g / ncolq, j = (g % ncolq) << 2;
    float4 va = *reinterpret_cast<const float4*>(a + (size_t)m * lda_a + j);
    float4 vb = *reinterpret_cast<const float4*>(b + (size_t)m * lda_b + j);
    float4 vo = {va.x + vb.x, va.y + vb.y, va.z + vb.z, va.w + vb.w};
    *reinterpret_cast<float4*>(o + (size_t)g * 4) = vo;
}

// ---------------- strided fp32 -> output-dtype cast, vectorized x4 ----------------
__global__ void cast_kernel(const float* __restrict__ src, int lda, int col0, int ncolq,
                            void* __restrict__ out, size_t obase, int total4,
                            const int* __restrict__ dflag) {
    const int bf = *dflag;
    int g = blockIdx.x * blockDim.x + threadIdx.x;
    if (g >= total4) return;
    int m = g / ncolq, j = (g % ncolq) << 2;
    float4 v = *reinterpret_cast<const float4*>(src + (size_t)m * lda + col0 + j);
    if (bf) {
        ushort4 h;
        h.x = f2bfu(v.x); h.y = f2bfu(v.y); h.z = f2bfu(v.z); h.w = f2bfu(v.w);
        *reinterpret_cast<ushort4*>((u16*)out + obase + (size_t)g * 4) = h;
    } else {
        *reinterpret_cast<float4*>((float*)out + obase + (size_t)g * 4) = v;
    }
}

// ---------------- fused cw_dist (fp64) + exact argmin ----------------
// grid (c=64, btile=16); block 256 = 4 waves; block covers 32 b-rows x 1024 s.
// Per thread: 8 b-rows as 2 groups of 4 scalar fp64 accumulators.
// bs read once per e-pair (float2, per-lane); xs read as broadcast double2 (b128).
// #pragma unroll 1 on st-loop: prevents the full-unroll + cross-barrier pipelining
// that spilled acc state to scratch in the previous version (14.5 GB traffic).
__global__ __launch_bounds__(256, 4) void dist_kernel(const float* __restrict__ cwr,
                                                      const void* __restrict__ book,
                                                      const double* __restrict__ bn,
                                                      void* __restrict__ out,
                                                      size_t odist, size_t oidx,
                                                      const int* __restrict__ dflag) {
    const int bf = *dflag;
    __shared__ double xs[32][64];   // 16 KB
    __shared__ double xn[32];
    __shared__ float bs[64][66];    // float2-aligned; ~2-way eff. bank aliasing (free)
    int t = threadIdx.x;
    int c = blockIdx.x;
    int b0 = blockIdx.y * 32;
    int sl = t & 63, wv = t >> 6;

    for (int i = t; i < 32 * 64; i += 256) {
        int bl = i >> 6, e = i & 63;
        xs[bl][e] = (double)cwr[(size_t)(b0 + bl) * CW_DIM + c * DIM_EMBED + e];
    }
    __syncthreads();
    if (t < 32) {
        double a = 0.0;
        for (int e = 0; e < 64; e++) a = fma(xs[t][e], xs[t][e], a);
        xn[t] = a;
    }

    double bd[8];
    int bsx[8];
#pragma unroll
    for (int p = 0; p < 8; p++) { bd[p] = 1e300; bsx[p] = 0; }

#pragma unroll 1
    for (int st = 0; st < 16; st++) {
        int s0 = st * 64;
        __syncthreads();  // previous-tile readers done (and xn visible on st==0)
#pragma unroll
        for (int i4 = t; i4 < 1024; i4 += 256) {
            int srow = i4 >> 4, e4 = (i4 & 15) << 2;
            float4 v = load4(book, ((size_t)c * BOOK_SIZE + s0 + srow) * DIM_EMBED + e4, bf);
            bs[srow][e4 + 0] = v.x; bs[srow][e4 + 1] = v.y;
            bs[srow][e4 + 2] = v.z; bs[srow][e4 + 3] = v.w;
        }
        __syncthreads();
        double bnv = bn[(size_t)c * BOOK_SIZE + s0 + sl];
#pragma unroll
        for (int pb = 0; pb < 2; pb++) {   // fully unrolled (2): bd/bsx indices stay compile-time
            int blb = wv * 8 + pb * 4;
            double a0 = 0.0, a1 = 0.0, a2 = 0.0, a3 = 0.0;
#pragma unroll 8
            for (int e = 0; e < 64; e += 2) {
                float2 bv = *(const float2*)&bs[sl][e];
                double bv0 = (double)bv.x, bv1 = (double)bv.y;
                double2 x0 = *(const double2*)&xs[blb + 0][e];
                double2 x1 = *(const double2*)&xs[blb + 1][e];
                double2 x2 = *(const double2*)&xs[blb + 2][e];
                double2 x3 = *(const double2*)&xs[blb + 3][e];
                a0 = fma(x0.x, bv0, a0); a0 = fma(x0.y, bv1, a0);
                a1 = fma(x1.x, bv0, a1); a1 = fma(x1.y, bv1, a1);
                a2 = fma(x2.x, bv0, a2); a2 = fma(x2.y, bv1, a2);
                a3 = fma(x3.x, bv0, a3); a3 = fma(x3.y, bv1, a3);
            }
            double dv[4];
            dv[0] = a0; dv[1] = a1; dv[2] = a2; dv[3] = a3;
#pragma unroll
            for (int j = 0; j < 4; j++) {
                int bl = blb + j;
                double d = xn[bl] + bnv - 2.0 * dv[j];
                stored(out, odist + ((size_t)(b0 + bl) * DIM_CODES + c) * BOOK_SIZE + s0 + sl, bf, d);
                if (d < bd[pb * 4 + j]) { bd[pb * 4 + j] = d; bsx[pb * 4 + j] = s0 + sl; }
            }
        }
    }
#pragma unroll
    for (int p = 0; p < 8; p++) {
        double d = bd[p];
        int s = bsx[p];
        for (int off = 32; off >= 1; off >>= 1) {
            double od = __shfl_xor(d, off, 64);
            int os = __shfl_xor(s, off, 64);
            if (od < d || (od == d && os < s)) { d = od; s = os; }
        }
        if (sl == 0)
            stored(out, oidx + (size_t)(b0 + wv * 8 + p) * DIM_CODES + c, bf, (double)s);
    }
}

extern "C" void kernel_launch(void* const* d_in, const int* in_sizes, int n_in,
                              void* d_out, int out_size, void* d_ws, size_t ws_size,
                              hipStream_t stream) {
    const void* x        = d_in[0];
    const void* codebook = d_in[1];
    const void* enc_w1   = d_in[2];
    const void* enc_b1   = d_in[3];
    const void* enc_w2   = d_in[4];
    const void* enc_b2   = d_in[5];
    const void* inf1_w   = d_in[6];
    const void* inf1_b   = d_in[7];
    const void* inf2_w1  = d_in[8];
    const void* inf2_b1  = d_in[9];
    const void* inf2_w2  = d_in[10];
    const void* inf2_b2  = d_in[11];
    const void* prior_w1 = d_in[12];
    const void* prior_b1 = d_in[13];
    const void* prior_w2 = d_in[14];
    const void* prior_b2 = d_in[15];
    const void* dec_w1   = d_in[16];
    const void* dec_b1   = d_in[17];
    const void* dec_w2   = d_in[18];
    const void* dec_b2   = d_in[19];

    // ---- fp32 workspace with aliasing (~26 MB) ----
    float* W0 = (float*)d_ws;
    float* inf1out = W0;                   // 512*512           [live to end]
    float* pfull   = inf1out + 262144;     // 512*1536          [live to end]
    float* dfull   = pfull + 786432;       // 512*1536          [live to end]
    float* cwr     = dfull + 786432;       // 512*4096          [live to end]
    float* bufA    = cwr + 2097152;        // 512*2048: h2, later dech
    float* bufB    = bufA + 1048576;       // 512*2048: p1, later d1
    float* bufC    = bufB + 1048576;       // 512*768: hmax(512*512), later z2
    double* bn     = (double*)(bufC + 393216);  // 64*1024 doubles (offset 8B-aligned)
    int* dflag     = (int*)(bn + 65536);

    // ---- output slice element offsets (return order) ----
    const size_t o_cwrecon = 0;
    const size_t o_cwdist  = 2097152;
    const size_t o_idx     = 35651584;
    const size_t o_mu      = 35684352;
    const size_t o_logvar  = 35815424;
    const size_t o_dmu     = 35946496;
    const size_t o_dlogvar = 36339712;
    const size_t o_plogvar = 36732928;

    detect_kernel<<<1, 256, 0, stream>>>((const u16*)x, dflag);
    booknorm_kernel<<<256, 256, 0, stream>>>(codebook, bn, dflag);
    enc_kernel<<<dim3(8, BATCH), 256, 0, stream>>>(x, enc_w1, enc_b1, bufC, dflag);  // hmax -> bufC

    // h2 = hmax @ enc_w2^T
    gemm_kernel<<<dim3(32, 8), 256, 0, stream>>>(bufC, 512, 512, bufC, 512, 512,
                                                 enc_w2, enc_b2, bufA, 2048, 0, dflag);
    // inf1out = h2 @ inf1_w^T (mu | log_var)
    gemm_kernel<<<dim3(8, 8), 256, 0, stream>>>(bufA, 2048, 2048, bufA, 2048, 2048,
                                                inf1_w, inf1_b, inf1out, 512, 0, dflag);
    // p1 = lrelu(z1 @ prior_w1^T); z1 = inf1out[:, :256]
    gemm_kernel<<<dim3(32, 8), 256, 0, stream>>>(inf1out, 512, 256, inf1out, 512, 256,
                                                 prior_w1, prior_b1, bufB, 2048, 1, dflag);
    // pfull = p1 @ prior_w2^T
    gemm_kernel<<<dim3(24, 8), 256, 0, stream>>>(bufB, 2048, 2048, bufB, 2048, 2048,
                                                 prior_w2, prior_b2, pfull, 1536, 0, dflag);
    // d1 = lrelu(concat(z1, h2) @ inf2_w1^T)   (overwrites p1, dead)
    gemm_kernel<<<dim3(32, 8), 256, 0, stream>>>(inf1out, 512, 256, bufA, 2048, 2304,
                                                 inf2_w1, inf2_b1, bufB, 2048, 1, dflag);
    // dfull = d1 @ inf2_w2^T
    gemm_kernel<<<dim3(24, 8), 256, 0, stream>>>(bufB, 2048, 2048, bufB, 2048, 2048,
                                                 inf2_w2, inf2_b2, dfull, 1536, 0, dflag);
    // z2 = dfull[:, :768] + pfull[:, :768]   (hmax dead -> bufC)
    add_kernel<<<384, 256, 0, stream>>>(dfull, 1536, pfull, 1536, bufC, 192, 98304);
    // dech = lrelu(z2 @ dec_w1^T)   (h2 dead -> bufA)
    gemm_kernel<<<dim3(32, 8), 256, 0, stream>>>(bufC, 768, 768, bufC, 768, 768,
                                                 dec_w1, dec_b1, bufA, 2048, 1, dflag);
    // cwr = dech @ dec_w2^T
    gemm_kernel<<<dim3(64, 8), 256, 0, stream>>>(bufA, 2048, 2048, bufA, 2048, 2048,
                                                 dec_w2, dec_b2, cwr, 4096, 0, dflag);

    // fused distances + argmin (writes o_cwdist and o_idx directly; fp64 kept here)
    dist_kernel<<<dim3(64, 16), 256, 0, stream>>>(cwr, codebook, bn,
                                                  d_out, o_cwdist, o_idx, dflag);

    // output casts (vectorized x4)
    cast_kernel<<<2048, 256, 0, stream>>>(cwr, 4096, 0, 1024, d_out, o_cwrecon, 524288, dflag);
    cast_kernel<<<128, 256, 0, stream>>>(inf1out, 512, 0, 64, d_out, o_mu, 32768, dflag);
    cast_kernel<<<128, 256, 0, stream>>>(inf1out, 512, 256, 64, d_out, o_logvar, 32768, dflag);
    cast_kernel<<<384, 256, 0, stream>>>(dfull, 1536, 0, 192, d_out, o_dmu, 98304, dflag);
    cast_kernel<<<384, 256, 0, stream>>>(dfull, 1536, 768, 192, d_out, o_dlogvar, 98304, dflag);
    cast_kernel<<<384, 256, 0, stream>>>(pfull, 1536, 768, 192, d_out, o_plogvar, 98304, dflag);
}